// Round 1
// baseline (971.170 us; speedup 1.0000x reference)
//
#include <hip/hip_runtime.h>
#include <math.h>

#define BB 64
#define LL 1024
#define EE 256
#define KK 8
#define NAUG 272     // 256 Kp cols + 16 v cols
#define EPB 16       // e-channels per xcorr block
#define CHUNKS (EE/EPB)

// workspace layout (units: floats)
#define O_MAUG   ((size_t)0)                   // 272*256 = 69632
#define O_BVAUG  ((size_t)69632)               // 16 (pad to 64)
#define O_KP     ((size_t)69696)               // B*L*E = 16777216
#define O_VSUB   (O_KP + (size_t)16777216)     // B*L*16 = 1048576
#define O_PPART  (O_VSUB + (size_t)1048576)    // B*CHUNKS*513*2 = 1050624
#define O_MV     (O_PPART + (size_t)1050624)   // B*L = 65536
#define O_STATS  (O_MV + (size_t)65536)        // ints + w0/w1

__device__ __forceinline__ float2 cmulf(float2 a, float2 b) {
    return make_float2(a.x * b.x - a.y * b.y, a.x * b.y + a.y * b.x);
}

// ---------------- kernel 1: Maug = [Wq^T Wk ; Wv rows 0..7 ; Wv rows 248..255]
__global__ __launch_bounds__(256) void build_maug(
    const float* __restrict__ Wq, const float* __restrict__ Wk,
    const float* __restrict__ Wv, const float* __restrict__ bv,
    float* __restrict__ maug, float* __restrict__ bvaug) {
    int i = blockIdx.x;   // 0..271 output row
    int j = threadIdx.x;  // 0..255 output col
    float acc = 0.f;
    if (i < EE) {
        for (int e = 0; e < EE; ++e)
            acc += Wq[e * EE + i] * Wk[e * EE + j];
    } else {
        int t = i - EE;
        int c = (t < 8) ? t : (240 + t);   // 0..7 then 248..255
        acc = Wv[c * EE + j];
    }
    maug[i * EE + j] = acc;
    if (i == 0 && j < 16) bvaug[j] = bv[(j < 8) ? j : (240 + j)];
}

// ---------------- kernel 2: GEMM  out[s, i] = sum_j T[s,j] * Maug[i,j]
// rows = B*L = 65536, cols = 272 (256 -> Kp, 16 -> vsub+bv)
__global__ __launch_bounds__(256) void gemm_kernel(
    const float* __restrict__ T, const float* __restrict__ maug,
    const float* __restrict__ bvaug,
    float* __restrict__ kp, float* __restrict__ vsub) {
    __shared__ float Ts[64][33];
    __shared__ float Ms[NAUG][33];
    const int tid = threadIdx.x;
    const int tx = tid & 15, ty = tid >> 4;
    const size_t s0 = (size_t)blockIdx.x * 64;

    float acc[4][17];
#pragma unroll
    for (int r = 0; r < 4; ++r)
#pragma unroll
        for (int c = 0; c < 17; ++c) acc[r][c] = 0.f;

    for (int kb = 0; kb < EE; kb += 32) {
        __syncthreads();
#pragma unroll
        for (int i = 0; i < 8; ++i) {           // 64*32 = 2048 = 256*8
            int idx = tid + 256 * i;
            int r = idx >> 5, c = idx & 31;
            Ts[r][c] = T[(s0 + r) * EE + kb + c];
        }
#pragma unroll
        for (int i = 0; i < 34; ++i) {          // 272*32 = 8704 = 256*34
            int idx = tid + 256 * i;
            int r = idx >> 5, c = idx & 31;
            Ms[r][c] = maug[r * EE + kb + c];
        }
        __syncthreads();
#pragma unroll
        for (int kk = 0; kk < 32; ++kk) {
            float a[4], bv2[17];
#pragma unroll
            for (int r = 0; r < 4; ++r) a[r] = Ts[ty + 16 * r][kk];
#pragma unroll
            for (int c = 0; c < 17; ++c) bv2[c] = Ms[tx + 16 * c][kk];
#pragma unroll
            for (int r = 0; r < 4; ++r)
#pragma unroll
                for (int c = 0; c < 17; ++c) acc[r][c] += a[r] * bv2[c];
        }
    }
#pragma unroll
    for (int r = 0; r < 4; ++r) {
        size_t row = s0 + ty + 16 * r;
#pragma unroll
        for (int c = 0; c < 16; ++c)
            kp[row * EE + tx + 16 * c] = acc[r][c];
        vsub[row * 16 + tx] = acc[r][16] + bvaug[tx];
    }
}

// ---------------- Stockham radix-2 complex FFT, N=1024, 256 threads
// result lands back in `a` (10 stages = even number of ping-pongs)
__device__ void fft1024(float2* a, float2* b, const float2* __restrict__ tw,
                        int tid, bool inverse) {
    float2* src = a;
    float2* dst = b;
#pragma unroll
    for (int t = 0; t < 10; ++t) {
        __syncthreads();
        const int Ns = 1 << t;
#pragma unroll
        for (int u = 0; u < 2; ++u) {
            int j = tid + (u << 8);              // 0..511
            int k = j & (Ns - 1);
            float2 w = tw[k << (9 - t)];         // e^{-2pi i k/(2Ns)}
            if (inverse) w.y = -w.y;
            float2 A = src[j];
            float2 Bv = src[j + 512];
            float2 Tv = cmulf(w, Bv);
            int base = ((j >> t) << (t + 1)) + k;
            dst[base] = make_float2(A.x + Tv.x, A.y + Tv.y);
            dst[base + Ns] = make_float2(A.x - Tv.x, A.y - Tv.y);
        }
        float2* tmp = src; src = dst; dst = tmp;
    }
    __syncthreads();
}

// ---------------- kernel 3: per (b, e-chunk): two-for-one FFT + cross-power partials
__global__ __launch_bounds__(256) void xcorr_kernel(
    const float* __restrict__ S, const float* __restrict__ kp,
    float* __restrict__ ppart) {
    __shared__ float2 bufA[1024];
    __shared__ float2 bufB[1024];
    __shared__ float2 tw[512];
    __shared__ float2 pacc[513];
    const int tid = threadIdx.x;
    const int b = blockIdx.x / CHUNKS;
    const int chunk = blockIdx.x % CHUNKS;

    for (int m = tid; m < 512; m += 256) {
        float sv, cv;
        sincosf(-2.f * 3.14159265358979323846f * (float)m / 1024.f, &sv, &cv);
        tw[m] = make_float2(cv, sv);
    }
    for (int f = tid; f <= 512; f += 256) pacc[f] = make_float2(0.f, 0.f);

    const size_t base = (size_t)b * LL * EE;
    for (int ee = 0; ee < EPB; ++ee) {
        const int e = chunk * EPB + ee;
        __syncthreads();   // previous iteration's pacc reads of bufA done
#pragma unroll
        for (int u = 0; u < 4; ++u) {
            int l = tid + (u << 8);
            size_t idx = base + (size_t)l * EE + e;
            bufA[l] = make_float2(S[idx], kp[idx]);   // pack s + i*kp
        }
        fft1024(bufA, bufB, tw, tid, false);
        // P += Sf * conj(Kpf) = 0.5*Im(A*C) + 0.25i*(|A|^2 - |C|^2), C = X[N-f]
        for (int f = tid; f <= 512; f += 256) {
            float2 A = bufA[f];
            float2 C = bufA[(1024 - f) & 1023];
            pacc[f].x += 0.5f * (A.x * C.y + A.y * C.x);
            pacc[f].y += 0.25f * ((A.x * A.x + A.y * A.y) - (C.x * C.x + C.y * C.y));
        }
    }
    __syncthreads();
    float* pp = ppart + (size_t)(b * CHUNKS + chunk) * 513 * 2;
    for (int f = tid; f <= 512; f += 256) {
        pp[2 * f] = pacc[f].x;
        pp[2 * f + 1] = pacc[f].y;
    }
}

// ---------------- kernel 4: per b: reduce partials, Hermitian irfft -> mean_value
__global__ __launch_bounds__(256) void ifft_kernel(
    const float* __restrict__ ppart, float* __restrict__ mv) {
    __shared__ float2 bufA[1024];
    __shared__ float2 bufB[1024];
    __shared__ float2 tw[512];
    const int tid = threadIdx.x;
    const int b = blockIdx.x;
    for (int m = tid; m < 512; m += 256) {
        float sv, cv;
        sincosf(-2.f * 3.14159265358979323846f * (float)m / 1024.f, &sv, &cv);
        tw[m] = make_float2(cv, sv);
    }
    for (int f = tid; f <= 512; f += 256) {
        float re = 0.f, im = 0.f;
        for (int c = 0; c < CHUNKS; ++c) {
            const float* pp = ppart + ((size_t)(b * CHUNKS + c) * 513 + f) * 2;
            re += pp[0];
            im += pp[1];
        }
        if (f == 0 || f == 512) im = 0.f;   // match irfft Hermitian semantics
        bufA[f] = make_float2(re, im);
        if (f > 0 && f < 512) bufA[1024 - f] = make_float2(re, -im);
    }
    fft1024(bufA, bufB, tw, tid, true);     // un-normalized inverse DFT
    const float sc = 1.f / (1024.f * 256.f); // 1/N (irfft) * 1/E (mean)
#pragma unroll
    for (int u = 0; u < 4; ++u) {
        int t = tid + (u << 8);
        mv[(size_t)b * LL + t] = bufA[t].x * sc;
    }
}

// ---------------- kernel 5: batch-mean over b, argmax/argmin over tau
__global__ __launch_bounds__(1024) void argidx_kernel(
    const float* __restrict__ mv, int* __restrict__ istats) {
    __shared__ float smax[1024], smin[1024];
    __shared__ int imax[1024], imin[1024];
    const int t = threadIdx.x;
    float g = 0.f;
    for (int b = 0; b < BB; ++b) g += mv[(size_t)b * LL + t];
    smax[t] = g; smin[t] = g; imax[t] = t; imin[t] = t;
    __syncthreads();
    for (int s = 512; s > 0; s >>= 1) {
        if (t < s) {
            if (smax[t + s] > smax[t] ||
                (smax[t + s] == smax[t] && imax[t + s] < imax[t])) {
                smax[t] = smax[t + s]; imax[t] = imax[t + s];
            }
            if (smin[t + s] < smin[t] ||
                (smin[t + s] == smin[t] && imin[t + s] > imin[t])) {
                smin[t] = smin[t + s]; imin[t] = imin[t + s];
            }
        }
        __syncthreads();
    }
    if (t == 0) { istats[0] = imax[0]; istats[1] = imin[0]; }
}

// ---------------- kernel 6: per-b softmax weights at idx0 / idx1
__global__ __launch_bounds__(256) void softmax_kernel(
    const float* __restrict__ mv, const int* __restrict__ istats,
    float* __restrict__ w01) {
    __shared__ float red[256];
    const int b = blockIdx.x, t = threadIdx.x;
    const float scale = 0.0625f;  // 1/sqrt(256)
    const float* row = mv + (size_t)b * LL;
    float m = -INFINITY;
    for (int i = t; i < LL; i += 256) m = fmaxf(m, row[i]);
    red[t] = m; __syncthreads();
    for (int s = 128; s > 0; s >>= 1) {
        if (t < s) red[t] = fmaxf(red[t], red[t + s]);
        __syncthreads();
    }
    m = red[0]; __syncthreads();
    float sum = 0.f;
    for (int i = t; i < LL; i += 256) sum += expf((row[i] - m) * scale);
    red[t] = sum; __syncthreads();
    for (int s = 128; s > 0; s >>= 1) {
        if (t < s) red[t] += red[t + s];
        __syncthreads();
    }
    if (t == 0) {
        float denom = red[0];
        w01[b]      = expf((row[istats[0]] - m) * scale) / denom;
        w01[BB + b] = expf((row[istats[1]] - m) * scale) / denom;
    }
}

// ---------------- kernel 7: gather rolled vsub columns, scale, write out
__global__ __launch_bounds__(256) void out_kernel(
    const float* __restrict__ vsub, const int* __restrict__ istats,
    const float* __restrict__ w01, float* __restrict__ out) {
    const int i = blockIdx.x * 256 + threadIdx.x;   // 0 .. 2*B*L*K-1
    const int half = (i >= BB * LL * KK) ? 1 : 0;
    const int j = i - half * BB * LL * KK;
    const int b = j / (LL * KK);
    const int rem = j % (LL * KK);
    const int l = rem / KK, kk = rem % KK;
    const int sh = istats[half];
    const int lr = (l + sh) & (LL - 1);
    const float w = w01[half * BB + b];
    out[i] = vsub[(size_t)(b * LL + lr) * 16 + half * 8 + kk] * w;
}

extern "C" void kernel_launch(void* const* d_in, const int* in_sizes, int n_in,
                              void* d_out, int out_size, void* d_ws, size_t ws_size,
                              hipStream_t stream) {
    const float* S  = (const float*)d_in[0];  // series
    const float* T  = (const float*)d_in[1];  // text_series
    const float* Wq = (const float*)d_in[2];
    const float* Wk = (const float*)d_in[4];
    const float* Wv = (const float*)d_in[6];
    const float* bv = (const float*)d_in[7];
    // bq (d_in[3]) and bk (d_in[5]) provably do not affect the output.

    float* ws    = (float*)d_ws;
    float* maug  = ws + O_MAUG;
    float* bvaug = ws + O_BVAUG;
    float* kp    = ws + O_KP;
    float* vsub  = ws + O_VSUB;
    float* ppart = ws + O_PPART;
    float* mv    = ws + O_MV;
    float* stats = ws + O_STATS;
    int*   istats = (int*)stats;      // [0]=idx0, [1]=idx1
    float* w01    = stats + 8;        // w0[64], w1[64]

    build_maug<<<NAUG, 256, 0, stream>>>(Wq, Wk, Wv, bv, maug, bvaug);
    gemm_kernel<<<(BB * LL) / 64, 256, 0, stream>>>(T, maug, bvaug, kp, vsub);
    xcorr_kernel<<<BB * CHUNKS, 256, 0, stream>>>(S, kp, ppart);
    ifft_kernel<<<BB, 256, 0, stream>>>(ppart, mv);
    argidx_kernel<<<1, 1024, 0, stream>>>(mv, istats);
    softmax_kernel<<<BB, 256, 0, stream>>>(mv, istats, w01);
    out_kernel<<<(2 * BB * LL * KK) / 256, 256, 0, stream>>>(vsub, istats, w01, (float*)d_out);
}

// Round 2
// 442.868 us; speedup vs baseline: 2.1929x; 2.1929x over previous
//
#include <hip/hip_runtime.h>
#include <math.h>

#define BB 64
#define LL 1024
#define EE 256
#define KK 8
#define NAUG 272     // 256 Kp cols + 16 v cols
#define EPB 16       // e-channels per xcorr block
#define CHUNKS (EE/EPB)

// workspace layout (units: floats)
#define O_MAUG   ((size_t)0)                    // 272*256 = 69632
#define O_BVAUG  ((size_t)69632)                // 16 (pad to 64)
#define O_KPT    ((size_t)69696)                // B*E*L = 16777216 (transposed [b][e][l])
#define O_ST     (O_KPT + (size_t)16777216)     // B*E*L = 16777216 (transposed [b][e][l])
#define O_VSUB   (O_ST + (size_t)16777216)      // B*L*16 = 1048576
#define O_PPART  (O_VSUB + (size_t)1048576)     // B*CHUNKS*513*2 = 1050624
#define O_MV     (O_PPART + (size_t)1050624)    // B*L = 65536
#define O_STATS  (O_MV + (size_t)65536)         // ints + w0/w1

__device__ __forceinline__ float2 cmulf(float2 a, float2 b) {
    return make_float2(a.x * b.x - a.y * b.y, a.x * b.y + a.y * b.x);
}

// ---------------- kernel 1: Maug = [Wq^T Wk ; Wv rows 0..7 ; Wv rows 248..255]
__global__ __launch_bounds__(256) void build_maug(
    const float* __restrict__ Wq, const float* __restrict__ Wk,
    const float* __restrict__ Wv, const float* __restrict__ bv,
    float* __restrict__ maug, float* __restrict__ bvaug) {
    int i = blockIdx.x;   // 0..271 output row
    int j = threadIdx.x;  // 0..255 output col
    float acc = 0.f;
    if (i < EE) {
        for (int e = 0; e < EE; ++e)
            acc += Wq[e * EE + i] * Wk[e * EE + j];
    } else {
        int t = i - EE;
        int c = (t < 8) ? t : (240 + t);   // 0..7 then 248..255
        acc = Wv[c * EE + j];
    }
    maug[i * EE + j] = acc;
    if (i == 0 && j < 16) bvaug[j] = bv[(j < 8) ? j : (240 + j)];
}

// ---------------- kernel 1b: St[b][e][l] = S[b][l][e]  (LDS 32x32 tile transpose)
__global__ __launch_bounds__(256) void transpose_S(
    const float* __restrict__ S, float* __restrict__ St) {
    __shared__ float tile[32][33];
    const int b = blockIdx.z;
    const int l0 = blockIdx.x * 32, e0 = blockIdx.y * 32;
    const int tx = threadIdx.x & 31, ty = threadIdx.x >> 5;   // 32 x 8
#pragma unroll
    for (int i = 0; i < 32; i += 8)
        tile[ty + i][tx] = S[((size_t)b * LL + l0 + ty + i) * EE + e0 + tx];
    __syncthreads();
#pragma unroll
    for (int i = 0; i < 32; i += 8)
        St[((size_t)b * EE + e0 + ty + i) * LL + l0 + tx] = tile[tx][ty + i];
}

// ---------------- kernel 2: GEMM  out[s, i] = sum_j T[s,j] * Maug[i,j]
// rows = B*L = 65536, cols = 272 (256 -> kp_t transposed, 16 -> vsub+bv)
__global__ __launch_bounds__(256) void gemm_kernel(
    const float* __restrict__ T, const float* __restrict__ maug,
    const float* __restrict__ bvaug,
    float* __restrict__ kp_t, float* __restrict__ vsub) {
    __shared__ float Ts[64][33];
    __shared__ float Ms[NAUG][33];
    const int tid = threadIdx.x;
    const int tx = tid & 15, ty = tid >> 4;
    const size_t s0 = (size_t)blockIdx.x * 64;
    const int bb = (int)(s0 >> 10);       // batch (64 | 1024 so constant per block)
    const int l0 = (int)(s0 & 1023);

    float acc[4][17];
#pragma unroll
    for (int r = 0; r < 4; ++r)
#pragma unroll
        for (int c = 0; c < 17; ++c) acc[r][c] = 0.f;

    for (int kb = 0; kb < EE; kb += 32) {
        __syncthreads();
#pragma unroll
        for (int i = 0; i < 8; ++i) {           // 64*32 = 2048 = 256*8
            int idx = tid + 256 * i;
            int r = idx >> 5, c = idx & 31;
            Ts[r][c] = T[(s0 + r) * EE + kb + c];
        }
#pragma unroll
        for (int i = 0; i < 34; ++i) {          // 272*32 = 8704 = 256*34
            int idx = tid + 256 * i;
            int r = idx >> 5, c = idx & 31;
            Ms[r][c] = maug[r * EE + kb + c];
        }
        __syncthreads();
#pragma unroll
        for (int kk = 0; kk < 32; ++kk) {
            float a[4], bv2[17];
#pragma unroll
            for (int r = 0; r < 4; ++r) a[r] = Ts[ty + 16 * r][kk];
#pragma unroll
            for (int c = 0; c < 17; ++c) bv2[c] = Ms[tx + 16 * c][kk];
#pragma unroll
            for (int r = 0; r < 4; ++r)
#pragma unroll
                for (int c = 0; c < 17; ++c) acc[r][c] += a[r] * bv2[c];
        }
    }
    // vsub (c==16): direct write, [s][16] layout
#pragma unroll
    for (int r = 0; r < 4; ++r)
        vsub[(s0 + ty + 16 * r) * 16 + tx] = acc[r][16] + bvaug[tx];

    // kp transposed write: for each c-group, stage [64 s][16 e] in LDS, emit e-rows
    for (int c = 0; c < 16; ++c) {
        __syncthreads();
#pragma unroll
        for (int r = 0; r < 4; ++r)
            Ts[ty + 16 * r][tx] = acc[r][c];     // Ts[s_local][e_local], e = 16c + tx
        __syncthreads();
#pragma unroll
        for (int u = 0; u < 4; ++u) {
            int idx = tid + 256 * u;
            int el = idx >> 6, ll = idx & 63;    // 16 e-rows x 64 l each
            kp_t[((size_t)bb * EE + 16 * c + el) * LL + l0 + ll] = Ts[ll][el];
        }
    }
}

// ---------------- Stockham radix-2 complex FFT, N=1024, 256 threads
// result lands back in `a` (10 stages = even number of ping-pongs)
__device__ void fft1024(float2* a, float2* b, const float2* __restrict__ tw,
                        int tid, bool inverse) {
    float2* src = a;
    float2* dst = b;
#pragma unroll
    for (int t = 0; t < 10; ++t) {
        __syncthreads();
        const int Ns = 1 << t;
#pragma unroll
        for (int u = 0; u < 2; ++u) {
            int j = tid + (u << 8);              // 0..511
            int k = j & (Ns - 1);
            float2 w = tw[k << (9 - t)];         // e^{-2pi i k/(2Ns)}
            if (inverse) w.y = -w.y;
            float2 A = src[j];
            float2 Bv = src[j + 512];
            float2 Tv = cmulf(w, Bv);
            int base = ((j >> t) << (t + 1)) + k;
            dst[base] = make_float2(A.x + Tv.x, A.y + Tv.y);
            dst[base + Ns] = make_float2(A.x - Tv.x, A.y - Tv.y);
        }
        float2* tmp = src; src = dst; dst = tmp;
    }
    __syncthreads();
}

// ---------------- kernel 3: per (b, e-chunk): two-for-one FFT + cross-power partials
__global__ __launch_bounds__(256) void xcorr_kernel(
    const float* __restrict__ St, const float* __restrict__ kp_t,
    float* __restrict__ ppart) {
    __shared__ float2 bufA[1024];
    __shared__ float2 bufB[1024];
    __shared__ float2 tw[512];
    __shared__ float2 pacc[513];
    const int tid = threadIdx.x;
    const int b = blockIdx.x / CHUNKS;
    const int chunk = blockIdx.x % CHUNKS;

    for (int m = tid; m < 512; m += 256) {
        float sv, cv;
        sincosf(-2.f * 3.14159265358979323846f * (float)m / 1024.f, &sv, &cv);
        tw[m] = make_float2(cv, sv);
    }
    for (int f = tid; f <= 512; f += 256) pacc[f] = make_float2(0.f, 0.f);

    const size_t base = ((size_t)b * EE + chunk * EPB) * LL;
    for (int ee = 0; ee < EPB; ++ee) {
        const size_t rbase = base + (size_t)ee * LL;
        __syncthreads();   // previous iteration's pacc reads of bufA done
#pragma unroll
        for (int u = 0; u < 4; ++u) {
            int l = tid + (u << 8);
            bufA[l] = make_float2(St[rbase + l], kp_t[rbase + l]);  // s + i*kp
        }
        fft1024(bufA, bufB, tw, tid, false);
        // P += Sf * conj(Kpf) = 0.5*Im(A*C) + 0.25i*(|A|^2 - |C|^2), C = X[N-f]
        for (int f = tid; f <= 512; f += 256) {
            float2 A = bufA[f];
            float2 C = bufA[(1024 - f) & 1023];
            pacc[f].x += 0.5f * (A.x * C.y + A.y * C.x);
            pacc[f].y += 0.25f * ((A.x * A.x + A.y * A.y) - (C.x * C.x + C.y * C.y));
        }
    }
    __syncthreads();
    float* pp = ppart + (size_t)(b * CHUNKS + chunk) * 513 * 2;
    for (int f = tid; f <= 512; f += 256) {
        pp[2 * f] = pacc[f].x;
        pp[2 * f + 1] = pacc[f].y;
    }
}

// ---------------- kernel 4: per b: reduce partials, Hermitian irfft -> mean_value
__global__ __launch_bounds__(256) void ifft_kernel(
    const float* __restrict__ ppart, float* __restrict__ mv) {
    __shared__ float2 bufA[1024];
    __shared__ float2 bufB[1024];
    __shared__ float2 tw[512];
    const int tid = threadIdx.x;
    const int b = blockIdx.x;
    for (int m = tid; m < 512; m += 256) {
        float sv, cv;
        sincosf(-2.f * 3.14159265358979323846f * (float)m / 1024.f, &sv, &cv);
        tw[m] = make_float2(cv, sv);
    }
    for (int f = tid; f <= 512; f += 256) {
        float re = 0.f, im = 0.f;
        for (int c = 0; c < CHUNKS; ++c) {
            const float* pp = ppart + ((size_t)(b * CHUNKS + c) * 513 + f) * 2;
            re += pp[0];
            im += pp[1];
        }
        if (f == 0 || f == 512) im = 0.f;   // match irfft Hermitian semantics
        bufA[f] = make_float2(re, im);
        if (f > 0 && f < 512) bufA[1024 - f] = make_float2(re, -im);
    }
    fft1024(bufA, bufB, tw, tid, true);     // un-normalized inverse DFT
    const float sc = 1.f / (1024.f * 256.f); // 1/N (irfft) * 1/E (mean)
#pragma unroll
    for (int u = 0; u < 4; ++u) {
        int t = tid + (u << 8);
        mv[(size_t)b * LL + t] = bufA[t].x * sc;
    }
}

// ---------------- kernel 5: batch-mean over b, argmax/argmin over tau
__global__ __launch_bounds__(1024) void argidx_kernel(
    const float* __restrict__ mv, int* __restrict__ istats) {
    __shared__ float smax[1024], smin[1024];
    __shared__ int imax[1024], imin[1024];
    const int t = threadIdx.x;
    float g = 0.f;
    for (int b = 0; b < BB; ++b) g += mv[(size_t)b * LL + t];
    smax[t] = g; smin[t] = g; imax[t] = t; imin[t] = t;
    __syncthreads();
    for (int s = 512; s > 0; s >>= 1) {
        if (t < s) {
            if (smax[t + s] > smax[t] ||
                (smax[t + s] == smax[t] && imax[t + s] < imax[t])) {
                smax[t] = smax[t + s]; imax[t] = imax[t + s];
            }
            if (smin[t + s] < smin[t] ||
                (smin[t + s] == smin[t] && imin[t + s] > imin[t])) {
                smin[t] = smin[t + s]; imin[t] = imin[t + s];
            }
        }
        __syncthreads();
    }
    if (t == 0) { istats[0] = imax[0]; istats[1] = imin[0]; }
}

// ---------------- kernel 6: per-b softmax weights at idx0 / idx1
__global__ __launch_bounds__(256) void softmax_kernel(
    const float* __restrict__ mv, const int* __restrict__ istats,
    float* __restrict__ w01) {
    __shared__ float red[256];
    const int b = blockIdx.x, t = threadIdx.x;
    const float scale = 0.0625f;  // 1/sqrt(256)
    const float* row = mv + (size_t)b * LL;
    float m = -INFINITY;
    for (int i = t; i < LL; i += 256) m = fmaxf(m, row[i]);
    red[t] = m; __syncthreads();
    for (int s = 128; s > 0; s >>= 1) {
        if (t < s) red[t] = fmaxf(red[t], red[t + s]);
        __syncthreads();
    }
    m = red[0]; __syncthreads();
    float sum = 0.f;
    for (int i = t; i < LL; i += 256) sum += expf((row[i] - m) * scale);
    red[t] = sum; __syncthreads();
    for (int s = 128; s > 0; s >>= 1) {
        if (t < s) red[t] += red[t + s];
        __syncthreads();
    }
    if (t == 0) {
        float denom = red[0];
        w01[b]      = expf((row[istats[0]] - m) * scale) / denom;
        w01[BB + b] = expf((row[istats[1]] - m) * scale) / denom;
    }
}

// ---------------- kernel 7: gather rolled vsub columns, scale, write out
__global__ __launch_bounds__(256) void out_kernel(
    const float* __restrict__ vsub, const int* __restrict__ istats,
    const float* __restrict__ w01, float* __restrict__ out) {
    const int i = blockIdx.x * 256 + threadIdx.x;   // 0 .. 2*B*L*K-1
    const int half = (i >= BB * LL * KK) ? 1 : 0;
    const int j = i - half * BB * LL * KK;
    const int b = j / (LL * KK);
    const int rem = j % (LL * KK);
    const int l = rem / KK, kk = rem % KK;
    const int sh = istats[half];
    const int lr = (l + sh) & (LL - 1);
    const float w = w01[half * BB + b];
    out[i] = vsub[(size_t)(b * LL + lr) * 16 + half * 8 + kk] * w;
}

extern "C" void kernel_launch(void* const* d_in, const int* in_sizes, int n_in,
                              void* d_out, int out_size, void* d_ws, size_t ws_size,
                              hipStream_t stream) {
    const float* S  = (const float*)d_in[0];  // series
    const float* T  = (const float*)d_in[1];  // text_series
    const float* Wq = (const float*)d_in[2];
    const float* Wk = (const float*)d_in[4];
    const float* Wv = (const float*)d_in[6];
    const float* bv = (const float*)d_in[7];
    // bq (d_in[3]) and bk (d_in[5]) provably do not affect the output.

    float* ws    = (float*)d_ws;
    float* maug  = ws + O_MAUG;
    float* bvaug = ws + O_BVAUG;
    float* kp_t  = ws + O_KPT;
    float* st    = ws + O_ST;
    float* vsub  = ws + O_VSUB;
    float* ppart = ws + O_PPART;
    float* mv    = ws + O_MV;
    float* stats = ws + O_STATS;
    int*   istats = (int*)stats;      // [0]=idx0, [1]=idx1
    float* w01    = stats + 8;        // w0[64], w1[64]

    build_maug<<<NAUG, 256, 0, stream>>>(Wq, Wk, Wv, bv, maug, bvaug);
    dim3 gT(LL / 32, EE / 32, BB);
    transpose_S<<<gT, 256, 0, stream>>>(S, st);
    gemm_kernel<<<(BB * LL) / 64, 256, 0, stream>>>(T, maug, bvaug, kp_t, vsub);
    xcorr_kernel<<<BB * CHUNKS, 256, 0, stream>>>(st, kp_t, ppart);
    ifft_kernel<<<BB, 256, 0, stream>>>(ppart, mv);
    argidx_kernel<<<1, 1024, 0, stream>>>(mv, istats);
    softmax_kernel<<<BB, 256, 0, stream>>>(mv, istats, w01);
    out_kernel<<<(2 * BB * LL * KK) / 256, 256, 0, stream>>>(vsub, istats, w01, (float*)d_out);
}

// Round 4
// 209.058 us; speedup vs baseline: 4.6454x; 2.1184x over previous
//
#include <hip/hip_runtime.h>
#include <hip/hip_bf16.h>
#include <math.h>

#define BB 64
#define LL 1024
#define EE 256
#define KK 8
#define EPB 16       // e-channels per xcorr block
#define CHUNKS (EE/EPB)

typedef __attribute__((ext_vector_type(8))) short  bfrag;   // 8 bf16 (4 VGPRs)
typedef __attribute__((ext_vector_type(4))) short  short4v; // 4 bf16 (8B)
typedef __attribute__((ext_vector_type(4))) float  f32x4;

// workspace layout (units: floats)
#define O_MAUGV  ((size_t)0)                    // 16*256 = 4096 (f32 v-rows)
#define O_BVAUG  ((size_t)4096)                 // 16 (pad 64)
#define O_MHI    ((size_t)4160)                 // 256*256 bf16 = 32768 floats
#define O_MLO    ((size_t)36928)                // 32768
#define O_KPT    ((size_t)69696)                // B*E*L = 16777216 ([b][e][l])
#define O_ST     (O_KPT + (size_t)16777216)     // B*E*L = 16777216 ([b][e][l])
#define O_VSUB   (O_ST + (size_t)16777216)      // B*L*16 = 1048576
#define O_PPART  (O_VSUB + (size_t)1048576)     // B*CHUNKS*513*2 = 1050624
#define O_MV     (O_PPART + (size_t)1050624)    // B*L = 65536
#define O_STATS  (O_MV + (size_t)65536)         // ints + w0/w1

__device__ __forceinline__ float2 cmulf(float2 a, float2 b) {
    return make_float2(a.x * b.x - a.y * b.y, a.x * b.y + a.y * b.x);
}

__device__ __forceinline__ void splitbf(float x, unsigned short& h, unsigned short& l) {
    __hip_bfloat16 hb = __float2bfloat16(x);
    float hf = __bfloat162float(hb);
    __hip_bfloat16 lb = __float2bfloat16(x - hf);
    h = *(unsigned short*)&hb;
    l = *(unsigned short*)&lb;
}

// ---------------- kernel 1: Maug split: rows<256 -> bf16 hi/lo of Wq^T Wk; v-rows f32
__global__ __launch_bounds__(256) void build_maug(
    const float* __restrict__ Wq, const float* __restrict__ Wk,
    const float* __restrict__ Wv, const float* __restrict__ bv,
    unsigned short* __restrict__ mhi, unsigned short* __restrict__ mlo,
    float* __restrict__ maugv, float* __restrict__ bvaug) {
    int i = blockIdx.x;   // 0..271
    int j = threadIdx.x;  // 0..255
    if (i < EE) {
        float acc = 0.f;
        for (int e = 0; e < EE; ++e)
            acc += Wq[e * EE + i] * Wk[e * EE + j];
        unsigned short h, l;
        splitbf(acc, h, l);
        mhi[i * EE + j] = h;
        mlo[i * EE + j] = l;
    } else {
        int t = i - EE;
        int c = (t < 8) ? t : (240 + t);   // Wv rows 0..7 then 248..255
        maugv[t * EE + j] = Wv[c * EE + j];
    }
    if (i == 0 && j < 16) bvaug[j] = bv[(j < 8) ? j : (240 + j)];
}

// ---------------- kernel 1b: St[b][e][l] = S[b][l][e]  (LDS 32x32 tile transpose)
__global__ __launch_bounds__(256) void transpose_S(
    const float* __restrict__ S, float* __restrict__ St) {
    __shared__ float tile[32][33];
    const int b = blockIdx.z;
    const int l0 = blockIdx.x * 32, e0 = blockIdx.y * 32;
    const int tx = threadIdx.x & 31, ty = threadIdx.x >> 5;   // 32 x 8
#pragma unroll
    for (int i = 0; i < 32; i += 8)
        tile[ty + i][tx] = S[((size_t)b * LL + l0 + ty + i) * EE + e0 + tx];
    __syncthreads();
#pragma unroll
    for (int i = 0; i < 32; i += 8)
        St[((size_t)b * EE + e0 + ty + i) * LL + l0 + tx] = tile[tx][ty + i];
}

// ---------------- kernel 2: MFMA GEMM (bf16 split-3): kp_t[b][n][l] = sum_k T[s][k]*M[n][k]
// BM=64 (s), BN=256 (n, all of it), BK=32, 4 waves: wave w owns n in [64w, 64w+64)
__global__ __launch_bounds__(256, 3) void gemm_mfma(
    const float* __restrict__ T, const unsigned short* __restrict__ mhi,
    const unsigned short* __restrict__ mlo, float* __restrict__ kp_t) {
    __shared__ alignas(16) unsigned short Ahi[64 * 32];   // [row][k], XOR-swizzled 16B slots
    __shared__ alignas(16) unsigned short Alo[64 * 32];
    __shared__ alignas(16) unsigned short Bhi[256 * 32];
    __shared__ alignas(16) unsigned short Blo[256 * 32];
    const int tid = threadIdx.x;
    const int w = tid >> 6, lane = tid & 63;
    const int lrow = lane & 15, lk = lane >> 4;     // frag row, k-group
    const size_t s0 = (size_t)blockIdx.x * 64;
    const int bb = (int)(s0 >> 10), l0 = (int)(s0 & 1023);

    f32x4 acc[4][4];   // [m][c]
#pragma unroll
    for (int m = 0; m < 4; ++m)
#pragma unroll
        for (int c = 0; c < 4; ++c) acc[m][c] = (f32x4){0.f, 0.f, 0.f, 0.f};

    for (int kb = 0; kb < EE; kb += 32) {
        __syncthreads();
        // ---- stage A: T f32 64x32 -> split bf16 hi/lo (swizzled slots); 512 slots
#pragma unroll
        for (int u = 0; u < 2; ++u) {
            int slot = tid + 256 * u;            // 0..511
            int row = slot >> 3, kq = slot & 7;  // float4 index within row
            f32x4 tv = *(const f32x4*)&T[(s0 + row) * EE + kb + kq * 4];
            unsigned short h[4], l[4];
#pragma unroll
            for (int j = 0; j < 4; ++j) splitbf(tv[j], h[j], l[j]);
            int sl = (kq >> 1) ^ (row & 3);
            int off = row * 32 + sl * 8 + (kq & 1) * 4;
            short4v hv; hv[0] = (short)h[0]; hv[1] = (short)h[1]; hv[2] = (short)h[2]; hv[3] = (short)h[3];
            short4v lv; lv[0] = (short)l[0]; lv[1] = (short)l[1]; lv[2] = (short)l[2]; lv[3] = (short)l[3];
            *(short4v*)&Ahi[off] = hv;
            *(short4v*)&Alo[off] = lv;
        }
        // ---- stage B: Maug bf16 256x32 hi/lo (swizzled slots); 1024 slots
#pragma unroll
        for (int u = 0; u < 4; ++u) {
            int slot = tid + 256 * u;            // 0..1023
            int n = slot >> 2, kq = slot & 3;    // short8 index within row
            int sl = kq ^ (n & 3);
            bfrag vh = *(const bfrag*)&mhi[n * EE + kb + kq * 8];
            bfrag vl = *(const bfrag*)&mlo[n * EE + kb + kq * 8];
            *(bfrag*)&Bhi[n * 32 + sl * 8] = vh;
            *(bfrag*)&Blo[n * 32 + sl * 8] = vl;
        }
        __syncthreads();
        // ---- fragments + MFMA
        bfrag ah[4], al[4];
#pragma unroll
        for (int m = 0; m < 4; ++m) {
            int row = m * 16 + lrow;
            int off = row * 32 + ((lk ^ (row & 3)) * 8);
            ah[m] = *(const bfrag*)&Ahi[off];
            al[m] = *(const bfrag*)&Alo[off];
        }
#pragma unroll
        for (int c = 0; c < 4; ++c) {
            int n = w * 64 + c * 16 + lrow;
            int off = n * 32 + ((lk ^ (n & 3)) * 8);
            bfrag bh = *(const bfrag*)&Bhi[off];
            bfrag bl = *(const bfrag*)&Blo[off];
#pragma unroll
            for (int m = 0; m < 4; ++m) {
                acc[m][c] = __builtin_amdgcn_mfma_f32_16x16x32_bf16(ah[m], bh, acc[m][c], 0, 0, 0);
                acc[m][c] = __builtin_amdgcn_mfma_f32_16x16x32_bf16(ah[m], bl, acc[m][c], 0, 0, 0);
                acc[m][c] = __builtin_amdgcn_mfma_f32_16x16x32_bf16(al[m], bh, acc[m][c], 0, 0, 0);
            }
        }
    }
    // ---- epilogue: direct transposed stores; D map: col=lane&15, row=(lane>>4)*4+reg
#pragma unroll
    for (int m = 0; m < 4; ++m) {
        int srow = m * 16 + (lane >> 4) * 4;
#pragma unroll
        for (int c = 0; c < 4; ++c) {
            int n = w * 64 + c * 16 + (lane & 15);
            *(f32x4*)&kp_t[((size_t)(bb * EE + n)) * LL + l0 + srow] = acc[m][c];
        }
    }
}

// ---------------- kernel 2b: vsub[s][n] = sum_k T[s][k]*maugv[n][k] + bv (exact f32)
__global__ __launch_bounds__(256) void vsub_kernel(
    const float* __restrict__ T, const float* __restrict__ maugv,
    const float* __restrict__ bvaug, float* __restrict__ vsub) {
    __shared__ float Ts[64][68];
    __shared__ float Mv[16][68];
    const int tid = threadIdx.x;
    const size_t s0 = (size_t)blockIdx.x * 64;
    const int n = tid & 15, sg = (tid >> 4) * 4;
    float acc[4] = {0.f, 0.f, 0.f, 0.f};
    for (int kc = 0; kc < EE; kc += 64) {
        __syncthreads();
#pragma unroll
        for (int u = 0; u < 4; ++u) {
            int slot = tid + 256 * u;             // 0..1023
            int row = slot >> 4, kq = slot & 15;
            *(f32x4*)&Ts[row][kq * 4] = *(const f32x4*)&T[(s0 + row) * EE + kc + kq * 4];
        }
        {
            int n2 = tid >> 4, kq = tid & 15;
            *(f32x4*)&Mv[n2][kq * 4] = *(const f32x4*)&maugv[n2 * EE + kc + kq * 4];
        }
        __syncthreads();
#pragma unroll
        for (int k4 = 0; k4 < 16; ++k4) {
            f32x4 mv4 = *(const f32x4*)&Mv[n][k4 * 4];
#pragma unroll
            for (int j = 0; j < 4; ++j) {
                f32x4 ts = *(const f32x4*)&Ts[sg + j][k4 * 4];
                acc[j] += ts[0] * mv4[0] + ts[1] * mv4[1] + ts[2] * mv4[2] + ts[3] * mv4[3];
            }
        }
    }
    float bvv = bvaug[n];
#pragma unroll
    for (int j = 0; j < 4; ++j)
        vsub[(s0 + sg + j) * 16 + n] = acc[j] + bvv;
}

// ---------------- Stockham radix-2 complex FFT, N=1024, 256 threads
__device__ void fft1024(float2* a, float2* b, const float2* __restrict__ tw,
                        int tid, bool inverse) {
    float2* src = a;
    float2* dst = b;
#pragma unroll
    for (int t = 0; t < 10; ++t) {
        __syncthreads();
        const int Ns = 1 << t;
#pragma unroll
        for (int u = 0; u < 2; ++u) {
            int j = tid + (u << 8);              // 0..511
            int k = j & (Ns - 1);
            float2 w = tw[k << (9 - t)];
            if (inverse) w.y = -w.y;
            float2 A = src[j];
            float2 Bv = src[j + 512];
            float2 Tv = cmulf(w, Bv);
            int base = ((j >> t) << (t + 1)) + k;
            dst[base] = make_float2(A.x + Tv.x, A.y + Tv.y);
            dst[base + Ns] = make_float2(A.x - Tv.x, A.y - Tv.y);
        }
        float2* tmp = src; src = dst; dst = tmp;
    }
    __syncthreads();
}

// ---------------- kernel 3: per (b, e-chunk): two-for-one FFT + cross-power partials
__global__ __launch_bounds__(256) void xcorr_kernel(
    const float* __restrict__ St, const float* __restrict__ kp_t,
    float* __restrict__ ppart) {
    __shared__ float2 bufA[1024];
    __shared__ float2 bufB[1024];
    __shared__ float2 tw[512];
    __shared__ float2 pacc[513];
    const int tid = threadIdx.x;
    const int b = blockIdx.x / CHUNKS;
    const int chunk = blockIdx.x % CHUNKS;

    for (int m = tid; m < 512; m += 256) {
        float sv, cv;
        sincosf(-2.f * 3.14159265358979323846f * (float)m / 1024.f, &sv, &cv);
        tw[m] = make_float2(cv, sv);
    }
    for (int f = tid; f <= 512; f += 256) pacc[f] = make_float2(0.f, 0.f);

    const size_t base = ((size_t)b * EE + chunk * EPB) * LL;
    for (int ee = 0; ee < EPB; ++ee) {
        const size_t rbase = base + (size_t)ee * LL;
        __syncthreads();
#pragma unroll
        for (int u = 0; u < 4; ++u) {
            int l = tid + (u << 8);
            bufA[l] = make_float2(St[rbase + l], kp_t[rbase + l]);  // s + i*kp
        }
        fft1024(bufA, bufB, tw, tid, false);
        for (int f = tid; f <= 512; f += 256) {
            float2 A = bufA[f];
            float2 C = bufA[(1024 - f) & 1023];
            pacc[f].x += 0.5f * (A.x * C.y + A.y * C.x);
            pacc[f].y += 0.25f * ((A.x * A.x + A.y * A.y) - (C.x * C.x + C.y * C.y));
        }
    }
    __syncthreads();
    float* pp = ppart + (size_t)(b * CHUNKS + chunk) * 513 * 2;
    for (int f = tid; f <= 512; f += 256) {
        pp[2 * f] = pacc[f].x;
        pp[2 * f + 1] = pacc[f].y;
    }
}

// ---------------- kernel 4: per b: reduce partials, Hermitian irfft -> mean_value
__global__ __launch_bounds__(256) void ifft_kernel(
    const float* __restrict__ ppart, float* __restrict__ mv) {
    __shared__ float2 bufA[1024];
    __shared__ float2 bufB[1024];
    __shared__ float2 tw[512];
    const int tid = threadIdx.x;
    const int b = blockIdx.x;
    for (int m = tid; m < 512; m += 256) {
        float sv, cv;
        sincosf(-2.f * 3.14159265358979323846f * (float)m / 1024.f, &sv, &cv);
        tw[m] = make_float2(cv, sv);
    }
    for (int f = tid; f <= 512; f += 256) {
        float re = 0.f, im = 0.f;
        for (int c = 0; c < CHUNKS; ++c) {
            const float* pp = ppart + ((size_t)(b * CHUNKS + c) * 513 + f) * 2;
            re += pp[0];
            im += pp[1];
        }
        if (f == 0 || f == 512) im = 0.f;
        bufA[f] = make_float2(re, im);
        if (f > 0 && f < 512) bufA[1024 - f] = make_float2(re, -im);
    }
    fft1024(bufA, bufB, tw, tid, true);
    const float sc = 1.f / (1024.f * 256.f);
#pragma unroll
    for (int u = 0; u < 4; ++u) {
        int t = tid + (u << 8);
        mv[(size_t)b * LL + t] = bufA[t].x * sc;
    }
}

// ---------------- kernel 5: batch-mean over b, argmax/argmin over tau
__global__ __launch_bounds__(1024) void argidx_kernel(
    const float* __restrict__ mv, int* __restrict__ istats) {
    __shared__ float smax[1024], smin[1024];
    __shared__ int imax[1024], imin[1024];
    const int t = threadIdx.x;
    float g = 0.f;
    for (int b = 0; b < BB; ++b) g += mv[(size_t)b * LL + t];
    smax[t] = g; smin[t] = g; imax[t] = t; imin[t] = t;
    __syncthreads();
    for (int s = 512; s > 0; s >>= 1) {
        if (t < s) {
            if (smax[t + s] > smax[t] ||
                (smax[t + s] == smax[t] && imax[t + s] < imax[t])) {
                smax[t] = smax[t + s]; imax[t] = imax[t + s];
            }
            if (smin[t + s] < smin[t] ||
                (smin[t + s] == smin[t] && imin[t + s] > imin[t])) {
                smin[t] = smin[t + s]; imin[t] = imin[t + s];
            }
        }
        __syncthreads();
    }
    if (t == 0) { istats[0] = imax[0]; istats[1] = imin[0]; }
}

// ---------------- kernel 6: per-b softmax weights at idx0 / idx1
__global__ __launch_bounds__(256) void softmax_kernel(
    const float* __restrict__ mv, const int* __restrict__ istats,
    float* __restrict__ w01) {
    __shared__ float red[256];
    const int b = blockIdx.x, t = threadIdx.x;
    const float scale = 0.0625f;  // 1/sqrt(256)
    const float* row = mv + (size_t)b * LL;
    float m = -INFINITY;
    for (int i = t; i < LL; i += 256) m = fmaxf(m, row[i]);
    red[t] = m; __syncthreads();
    for (int s = 128; s > 0; s >>= 1) {
        if (t < s) red[t] = fmaxf(red[t], red[t + s]);
        __syncthreads();
    }
    m = red[0]; __syncthreads();
    float sum = 0.f;
    for (int i = t; i < LL; i += 256) sum += expf((row[i] - m) * scale);
    red[t] = sum; __syncthreads();
    for (int s = 128; s > 0; s >>= 1) {
        if (t < s) red[t] += red[t + s];
        __syncthreads();
    }
    if (t == 0) {
        float denom = red[0];
        w01[b]      = expf((row[istats[0]] - m) * scale) / denom;
        w01[BB + b] = expf((row[istats[1]] - m) * scale) / denom;
    }
}

// ---------------- kernel 7: gather rolled vsub columns, scale, write out
__global__ __launch_bounds__(256) void out_kernel(
    const float* __restrict__ vsub, const int* __restrict__ istats,
    const float* __restrict__ w01, float* __restrict__ out) {
    const int i = blockIdx.x * 256 + threadIdx.x;   // 0 .. 2*B*L*K-1
    const int half = (i >= BB * LL * KK) ? 1 : 0;
    const int j = i - half * BB * LL * KK;
    const int b = j / (LL * KK);
    const int rem = j % (LL * KK);
    const int l = rem / KK, kk = rem % KK;
    const int sh = istats[half];
    const int lr = (l + sh) & (LL - 1);
    const float w = w01[half * BB + b];
    out[i] = vsub[(size_t)(b * LL + lr) * 16 + half * 8 + kk] * w;
}

extern "C" void kernel_launch(void* const* d_in, const int* in_sizes, int n_in,
                              void* d_out, int out_size, void* d_ws, size_t ws_size,
                              hipStream_t stream) {
    const float* S  = (const float*)d_in[0];  // series
    const float* T  = (const float*)d_in[1];  // text_series
    const float* Wq = (const float*)d_in[2];
    const float* Wk = (const float*)d_in[4];
    const float* Wv = (const float*)d_in[6];
    const float* bv = (const float*)d_in[7];
    // bq (d_in[3]) and bk (d_in[5]) provably do not affect the output.

    float* ws    = (float*)d_ws;
    float* maugv = ws + O_MAUGV;
    float* bvaug = ws + O_BVAUG;
    unsigned short* mhi = (unsigned short*)(ws + O_MHI);
    unsigned short* mlo = (unsigned short*)(ws + O_MLO);
    float* kp_t  = ws + O_KPT;
    float* st    = ws + O_ST;
    float* vsub  = ws + O_VSUB;
    float* ppart = ws + O_PPART;
    float* mv    = ws + O_MV;
    float* stats = ws + O_STATS;
    int*   istats = (int*)stats;      // [0]=idx0, [1]=idx1
    float* w01    = stats + 8;        // w0[64], w1[64]

    build_maug<<<272, 256, 0, stream>>>(Wq, Wk, Wv, bv, mhi, mlo, maugv, bvaug);
    dim3 gT(LL / 32, EE / 32, BB);
    transpose_S<<<gT, 256, 0, stream>>>(S, st);
    gemm_mfma<<<(BB * LL) / 64, 256, 0, stream>>>(T, mhi, mlo, kp_t);
    vsub_kernel<<<(BB * LL) / 64, 256, 0, stream>>>(T, maugv, bvaug, vsub);
    xcorr_kernel<<<BB * CHUNKS, 256, 0, stream>>>(st, kp_t, ppart);
    ifft_kernel<<<BB, 256, 0, stream>>>(ppart, mv);
    argidx_kernel<<<1, 1024, 0, stream>>>(mv, istats);
    softmax_kernel<<<BB, 256, 0, stream>>>(mv, istats, w01);
    out_kernel<<<(2 * BB * LL * KK) / 256, 256, 0, stream>>>(vsub, istats, w01, (float*)d_out);
}

// Round 5
// 176.841 us; speedup vs baseline: 5.4918x; 1.1822x over previous
//
#include <hip/hip_runtime.h>
#include <hip/hip_bf16.h>
#include <math.h>

#define BB 64
#define LL 1024
#define EE 256
#define KK 8
#define EPB 8        // e-channels per xcorr block
#define CHUNKS (EE/EPB)

typedef __attribute__((ext_vector_type(8))) short  bfrag;   // 8 bf16 (4 VGPRs)
typedef __attribute__((ext_vector_type(4))) short  short4v; // 4 bf16 (8B)
typedef __attribute__((ext_vector_type(4))) float  f32x4;

// workspace layout (units: floats)
#define O_MAUGV  ((size_t)0)                    // 16*256 = 4096 (f32 v-rows)
#define O_BVAUG  ((size_t)4096)                 // 16 (pad 64)
#define O_MHI    ((size_t)4160)                 // 256*256 bf16 = 32768 floats
#define O_MLO    ((size_t)36928)                // 32768
#define O_KPT    ((size_t)69696)                // B*E*L = 16777216 ([b][e][l])
#define O_ST     (O_KPT + (size_t)16777216)     // B*E*L = 16777216 ([b][e][l])
#define O_VSUB   (O_ST + (size_t)16777216)      // B*L*16 = 1048576
#define O_MV     (O_VSUB + (size_t)1048576)     // B*L = 65536
#define O_STATS  (O_MV + (size_t)65536)         // ints + w0/w1
// xcorr partials (513 float2 per (b,chunk)) are overlaid into the head of each
// block's own St slab (slab = EPB*LL floats = 8192 >= 1026) — St is fully
// consumed by that block before the write, and transpose_S rewrites St each call.

__device__ __forceinline__ float2 cmulf(float2 a, float2 b) {
    return make_float2(a.x * b.x - a.y * b.y, a.x * b.y + a.y * b.x);
}

__device__ __forceinline__ int PHY(int i) { return i + (i >> 4); }  // LDS pad: +1 float2 per 16

__device__ __forceinline__ void splitbf(float x, unsigned short& h, unsigned short& l) {
    __hip_bfloat16 hb = __float2bfloat16(x);
    float hf = __bfloat162float(hb);
    __hip_bfloat16 lb = __float2bfloat16(x - hf);
    h = *(unsigned short*)&hb;
    l = *(unsigned short*)&lb;
}

// ---------------- kernel 1: Maug split: rows<256 -> bf16 hi/lo of Wq^T Wk; v-rows f32
__global__ __launch_bounds__(256) void build_maug(
    const float* __restrict__ Wq, const float* __restrict__ Wk,
    const float* __restrict__ Wv, const float* __restrict__ bv,
    unsigned short* __restrict__ mhi, unsigned short* __restrict__ mlo,
    float* __restrict__ maugv, float* __restrict__ bvaug) {
    int i = blockIdx.x;   // 0..271
    int j = threadIdx.x;  // 0..255
    if (i < EE) {
        float acc = 0.f;
        for (int e = 0; e < EE; ++e)
            acc += Wq[e * EE + i] * Wk[e * EE + j];
        unsigned short h, l;
        splitbf(acc, h, l);
        mhi[i * EE + j] = h;
        mlo[i * EE + j] = l;
    } else {
        int t = i - EE;
        int c = (t < 8) ? t : (240 + t);   // Wv rows 0..7 then 248..255
        maugv[t * EE + j] = Wv[c * EE + j];
    }
    if (i == 0 && j < 16) bvaug[j] = bv[(j < 8) ? j : (240 + j)];
}

// ---------------- kernel 1b: St[b][e][l] = S[b][l][e]  (LDS 32x32 tile transpose)
__global__ __launch_bounds__(256) void transpose_S(
    const float* __restrict__ S, float* __restrict__ St) {
    __shared__ float tile[32][33];
    const int b = blockIdx.z;
    const int l0 = blockIdx.x * 32, e0 = blockIdx.y * 32;
    const int tx = threadIdx.x & 31, ty = threadIdx.x >> 5;   // 32 x 8
#pragma unroll
    for (int i = 0; i < 32; i += 8)
        tile[ty + i][tx] = S[((size_t)b * LL + l0 + ty + i) * EE + e0 + tx];
    __syncthreads();
#pragma unroll
    for (int i = 0; i < 32; i += 8)
        St[((size_t)b * EE + e0 + ty + i) * LL + l0 + tx] = tile[tx][ty + i];
}

// ---------------- kernel 2: MFMA GEMM (bf16 split-3): kp_t[b][n][l] = sum_k T[s][k]*M[n][k]
__global__ __launch_bounds__(256, 3) void gemm_mfma(
    const float* __restrict__ T, const unsigned short* __restrict__ mhi,
    const unsigned short* __restrict__ mlo, float* __restrict__ kp_t) {
    __shared__ alignas(16) unsigned short Ahi[64 * 32];
    __shared__ alignas(16) unsigned short Alo[64 * 32];
    __shared__ alignas(16) unsigned short Bhi[256 * 32];
    __shared__ alignas(16) unsigned short Blo[256 * 32];
    const int tid = threadIdx.x;
    const int w = tid >> 6, lane = tid & 63;
    const int lrow = lane & 15, lk = lane >> 4;
    const size_t s0 = (size_t)blockIdx.x * 64;
    const int bb = (int)(s0 >> 10), l0 = (int)(s0 & 1023);

    f32x4 acc[4][4];
#pragma unroll
    for (int m = 0; m < 4; ++m)
#pragma unroll
        for (int c = 0; c < 4; ++c) acc[m][c] = (f32x4){0.f, 0.f, 0.f, 0.f};

    for (int kb = 0; kb < EE; kb += 32) {
        __syncthreads();
#pragma unroll
        for (int u = 0; u < 2; ++u) {
            int slot = tid + 256 * u;            // 0..511
            int row = slot >> 3, kq = slot & 7;
            f32x4 tv = *(const f32x4*)&T[(s0 + row) * EE + kb + kq * 4];
            unsigned short h[4], l[4];
#pragma unroll
            for (int j = 0; j < 4; ++j) splitbf(tv[j], h[j], l[j]);
            int sl = (kq >> 1) ^ (row & 3);
            int off = row * 32 + sl * 8 + (kq & 1) * 4;
            short4v hv; hv[0] = (short)h[0]; hv[1] = (short)h[1]; hv[2] = (short)h[2]; hv[3] = (short)h[3];
            short4v lv; lv[0] = (short)l[0]; lv[1] = (short)l[1]; lv[2] = (short)l[2]; lv[3] = (short)l[3];
            *(short4v*)&Ahi[off] = hv;
            *(short4v*)&Alo[off] = lv;
        }
#pragma unroll
        for (int u = 0; u < 4; ++u) {
            int slot = tid + 256 * u;            // 0..1023
            int n = slot >> 2, kq = slot & 3;
            int sl = kq ^ (n & 3);
            bfrag vh = *(const bfrag*)&mhi[n * EE + kb + kq * 8];
            bfrag vl = *(const bfrag*)&mlo[n * EE + kb + kq * 8];
            *(bfrag*)&Bhi[n * 32 + sl * 8] = vh;
            *(bfrag*)&Blo[n * 32 + sl * 8] = vl;
        }
        __syncthreads();
        bfrag ah[4], al[4];
#pragma unroll
        for (int m = 0; m < 4; ++m) {
            int row = m * 16 + lrow;
            int off = row * 32 + ((lk ^ (row & 3)) * 8);
            ah[m] = *(const bfrag*)&Ahi[off];
            al[m] = *(const bfrag*)&Alo[off];
        }
#pragma unroll
        for (int c = 0; c < 4; ++c) {
            int n = w * 64 + c * 16 + lrow;
            int off = n * 32 + ((lk ^ (n & 3)) * 8);
            bfrag bh = *(const bfrag*)&Bhi[off];
            bfrag bl = *(const bfrag*)&Blo[off];
#pragma unroll
            for (int m = 0; m < 4; ++m) {
                acc[m][c] = __builtin_amdgcn_mfma_f32_16x16x32_bf16(ah[m], bh, acc[m][c], 0, 0, 0);
                acc[m][c] = __builtin_amdgcn_mfma_f32_16x16x32_bf16(ah[m], bl, acc[m][c], 0, 0, 0);
                acc[m][c] = __builtin_amdgcn_mfma_f32_16x16x32_bf16(al[m], bh, acc[m][c], 0, 0, 0);
            }
        }
    }
#pragma unroll
    for (int m = 0; m < 4; ++m) {
        int srow = m * 16 + (lane >> 4) * 4;
#pragma unroll
        for (int c = 0; c < 4; ++c) {
            int n = w * 64 + c * 16 + (lane & 15);
            *(f32x4*)&kp_t[((size_t)(bb * EE + n)) * LL + l0 + srow] = acc[m][c];
        }
    }
}

// ---------------- kernel 2b: vsub[s][n] = sum_k T[s][k]*maugv[n][k] + bv (exact f32)
__global__ __launch_bounds__(256) void vsub_kernel(
    const float* __restrict__ T, const float* __restrict__ maugv,
    const float* __restrict__ bvaug, float* __restrict__ vsub) {
    __shared__ float Ts[64][68];
    __shared__ float Mv[16][68];
    const int tid = threadIdx.x;
    const size_t s0 = (size_t)blockIdx.x * 64;
    const int n = tid & 15, sg = (tid >> 4) * 4;
    float acc[4] = {0.f, 0.f, 0.f, 0.f};
    for (int kc = 0; kc < EE; kc += 64) {
        __syncthreads();
#pragma unroll
        for (int u = 0; u < 4; ++u) {
            int slot = tid + 256 * u;
            int row = slot >> 4, kq = slot & 15;
            *(f32x4*)&Ts[row][kq * 4] = *(const f32x4*)&T[(s0 + row) * EE + kc + kq * 4];
        }
        {
            int n2 = tid >> 4, kq = tid & 15;
            *(f32x4*)&Mv[n2][kq * 4] = *(const f32x4*)&maugv[n2 * EE + kc + kq * 4];
        }
        __syncthreads();
#pragma unroll
        for (int k4 = 0; k4 < 16; ++k4) {
            f32x4 mv4 = *(const f32x4*)&Mv[n][k4 * 4];
#pragma unroll
            for (int j = 0; j < 4; ++j) {
                f32x4 ts = *(const f32x4*)&Ts[sg + j][k4 * 4];
                acc[j] += ts[0] * mv4[0] + ts[1] * mv4[1] + ts[2] * mv4[2] + ts[3] * mv4[3];
            }
        }
    }
    float bvv = bvaug[n];
#pragma unroll
    for (int j = 0; j < 4; ++j)
        vsub[(s0 + sg + j) * 16 + n] = acc[j] + bvv;
}

// ---------------- radix-4 Stockham FFT, N=1024, 5 stages, 256 threads.
// Buffers are PHY-padded (1088 float2). RESULT LANDS IN `b`.
template<bool INV>
__device__ __forceinline__ void fft1024_r4(float2* a, float2* b,
                                           const float2* __restrict__ tw, int tid) {
    float2* src = a;
    float2* dst = b;
#pragma unroll
    for (int t = 0; t < 5; ++t) {
        const int Ns = 1 << (2 * t);     // 1,4,16,64,256
        const int sh = 8 - 2 * t;
        __syncthreads();
        const int j = tid;
        const int k = j & (Ns - 1);
        float2 w1 = tw[k << sh];          // exp(-2pi i k/(4Ns))
        float2 w2 = tw[k << (sh + 1)];    // index < 512
        float2 w3 = cmulf(w1, w2);
        if (INV) { w1.y = -w1.y; w2.y = -w2.y; w3.y = -w3.y; }
        float2 a0 = src[PHY(j)];
        float2 a1 = cmulf(w1, src[PHY(j + 256)]);
        float2 a2 = cmulf(w2, src[PHY(j + 512)]);
        float2 a3 = cmulf(w3, src[PHY(j + 768)]);
        float2 t0 = make_float2(a0.x + a2.x, a0.y + a2.y);
        float2 t1 = make_float2(a0.x - a2.x, a0.y - a2.y);
        float2 t2 = make_float2(a1.x + a3.x, a1.y + a3.y);
        float2 t3 = make_float2(a1.x - a3.x, a1.y - a3.y);
        float2 u3 = INV ? make_float2(-t3.y, t3.x) : make_float2(t3.y, -t3.x);
        const int base = ((j >> (2 * t)) << (2 * t + 2)) + k;
        dst[PHY(base)]          = make_float2(t0.x + t2.x, t0.y + t2.y);
        dst[PHY(base + Ns)]     = make_float2(t1.x + u3.x, t1.y + u3.y);
        dst[PHY(base + 2 * Ns)] = make_float2(t0.x - t2.x, t0.y - t2.y);
        dst[PHY(base + 3 * Ns)] = make_float2(t1.x - u3.x, t1.y - u3.y);
        float2* tmp = src; src = dst; dst = tmp;
    }
    __syncthreads();
}

// ---------------- kernel 3: per (b, e-chunk): two-for-one FFT + cross-power partials
// Partials written into the head of this block's OWN St slab (already consumed).
__global__ __launch_bounds__(256) void xcorr_kernel(
    float* __restrict__ St, const float* __restrict__ kp_t) {
    __shared__ float2 bufA[1088];
    __shared__ float2 bufB[1088];
    __shared__ float2 tw[512];
    const int tid = threadIdx.x;
    const int b = blockIdx.x / CHUNKS;
    const int chunk = blockIdx.x % CHUNKS;

    for (int m = tid; m < 512; m += 256) {
        float sv, cv;
        sincosf(-2.f * 3.14159265358979323846f * (float)m / 1024.f, &sv, &cv);
        tw[m] = make_float2(cv, sv);
    }
    float2 p0 = make_float2(0.f, 0.f);
    float2 p1 = make_float2(0.f, 0.f);
    float px2 = 0.f;                      // f=512 (lane 0 only), imag is exactly 0

    const size_t base = ((size_t)b * EE + (size_t)chunk * EPB) * LL;
    for (int ee = 0; ee < EPB; ++ee) {
        const size_t rbase = base + (size_t)ee * LL;
#pragma unroll
        for (int u = 0; u < 4; ++u) {
            int l = tid + (u << 8);
            bufA[PHY(l)] = make_float2(St[rbase + l], kp_t[rbase + l]);  // s + i*kp
        }
        fft1024_r4<false>(bufA, bufB, tw, tid);   // result in bufB
        {   // f = tid
            float2 A = bufB[PHY(tid)];
            float2 C = bufB[PHY((1024 - tid) & 1023)];
            p0.x += 0.5f * (A.x * C.y + A.y * C.x);
            p0.y += 0.25f * ((A.x * A.x + A.y * A.y) - (C.x * C.x + C.y * C.y));
        }
        {   // f = tid + 256
            int f = tid + 256;
            float2 A = bufB[PHY(f)];
            float2 C = bufB[PHY(1024 - f)];
            p1.x += 0.5f * (A.x * C.y + A.y * C.x);
            p1.y += 0.25f * ((A.x * A.x + A.y * A.y) - (C.x * C.x + C.y * C.y));
        }
        if (tid == 0) {   // f = 512: C == A -> P = A.x*A.y + 0i
            float2 A = bufB[PHY(512)];
            px2 += A.x * A.y;
        }
    }
    float2* pp = (float2*)&St[base];      // own slab head, fully consumed above
    pp[tid] = p0;
    pp[tid + 256] = p1;
    if (tid == 0) pp[512] = make_float2(px2, 0.f);
}

// ---------------- kernel 4: per b: reduce partials, Hermitian irfft -> mean_value
__global__ __launch_bounds__(256) void ifft_kernel(
    const float* __restrict__ St, float* __restrict__ mv) {
    __shared__ float2 bufA[1088];
    __shared__ float2 bufB[1088];
    __shared__ float2 tw[512];
    const int tid = threadIdx.x;
    const int b = blockIdx.x;
    for (int m = tid; m < 512; m += 256) {
        float sv, cv;
        sincosf(-2.f * 3.14159265358979323846f * (float)m / 1024.f, &sv, &cv);
        tw[m] = make_float2(cv, sv);
    }
#pragma unroll
    for (int u = 0; u < 2; ++u) {
        int f = tid + (u << 8);            // 0..511
        float2 s = make_float2(0.f, 0.f);
        for (int c = 0; c < CHUNKS; ++c) {
            const float2* pp = (const float2*)&St[((size_t)b * EE + (size_t)c * EPB) * LL];
            float2 v = pp[f];
            s.x += v.x; s.y += v.y;
        }
        if (f == 0) s.y = 0.f;
        bufA[PHY(f)] = s;
        if (f > 0) bufA[PHY(1024 - f)] = make_float2(s.x, -s.y);
    }
    if (tid == 0) {
        float2 s = make_float2(0.f, 0.f);
        for (int c = 0; c < CHUNKS; ++c) {
            const float2* pp = (const float2*)&St[((size_t)b * EE + (size_t)c * EPB) * LL];
            float2 v = pp[512];
            s.x += v.x;
        }
        bufA[PHY(512)] = make_float2(s.x, 0.f);
    }
    fft1024_r4<true>(bufA, bufB, tw, tid);      // result in bufB
    const float sc = 1.f / (1024.f * 256.f);    // 1/N (irfft) * 1/E (mean)
#pragma unroll
    for (int u = 0; u < 4; ++u) {
        int t = tid + (u << 8);
        mv[(size_t)b * LL + t] = bufB[PHY(t)].x * sc;
    }
}

// ---------------- kernel 5: batch-mean over b, argmax/argmin over tau
__global__ __launch_bounds__(1024) void argidx_kernel(
    const float* __restrict__ mv, int* __restrict__ istats) {
    __shared__ float smax[1024], smin[1024];
    __shared__ int imax[1024], imin[1024];
    const int t = threadIdx.x;
    float g = 0.f;
    for (int b = 0; b < BB; ++b) g += mv[(size_t)b * LL + t];
    smax[t] = g; smin[t] = g; imax[t] = t; imin[t] = t;
    __syncthreads();
    for (int s = 512; s > 0; s >>= 1) {
        if (t < s) {
            if (smax[t + s] > smax[t] ||
                (smax[t + s] == smax[t] && imax[t + s] < imax[t])) {
                smax[t] = smax[t + s]; imax[t] = imax[t + s];
            }
            if (smin[t + s] < smin[t] ||
                (smin[t + s] == smin[t] && imin[t + s] > imin[t])) {
                smin[t] = smin[t + s]; imin[t] = imin[t + s];
            }
        }
        __syncthreads();
    }
    if (t == 0) { istats[0] = imax[0]; istats[1] = imin[0]; }
}

// ---------------- kernel 6: per-b softmax weights at idx0 / idx1
__global__ __launch_bounds__(256) void softmax_kernel(
    const float* __restrict__ mv, const int* __restrict__ istats,
    float* __restrict__ w01) {
    __shared__ float red[256];
    const int b = blockIdx.x, t = threadIdx.x;
    const float scale = 0.0625f;  // 1/sqrt(256)
    const float* row = mv + (size_t)b * LL;
    float m = -INFINITY;
    for (int i = t; i < LL; i += 256) m = fmaxf(m, row[i]);
    red[t] = m; __syncthreads();
    for (int s = 128; s > 0; s >>= 1) {
        if (t < s) red[t] = fmaxf(red[t], red[t + s]);
        __syncthreads();
    }
    m = red[0]; __syncthreads();
    float sum = 0.f;
    for (int i = t; i < LL; i += 256) sum += expf((row[i] - m) * scale);
    red[t] = sum; __syncthreads();
    for (int s = 128; s > 0; s >>= 1) {
        if (t < s) red[t] += red[t + s];
        __syncthreads();
    }
    if (t == 0) {
        float denom = red[0];
        w01[b]      = expf((row[istats[0]] - m) * scale) / denom;
        w01[BB + b] = expf((row[istats[1]] - m) * scale) / denom;
    }
}

// ---------------- kernel 7: gather rolled vsub columns, scale, write out
__global__ __launch_bounds__(256) void out_kernel(
    const float* __restrict__ vsub, const int* __restrict__ istats,
    const float* __restrict__ w01, float* __restrict__ out) {
    const int i = blockIdx.x * 256 + threadIdx.x;
    const int half = (i >= BB * LL * KK) ? 1 : 0;
    const int j = i - half * BB * LL * KK;
    const int b = j / (LL * KK);
    const int rem = j % (LL * KK);
    const int l = rem / KK, kk = rem % KK;
    const int sh = istats[half];
    const int lr = (l + sh) & (LL - 1);
    const float w = w01[half * BB + b];
    out[i] = vsub[(size_t)(b * LL + lr) * 16 + half * 8 + kk] * w;
}

extern "C" void kernel_launch(void* const* d_in, const int* in_sizes, int n_in,
                              void* d_out, int out_size, void* d_ws, size_t ws_size,
                              hipStream_t stream) {
    const float* S  = (const float*)d_in[0];  // series
    const float* T  = (const float*)d_in[1];  // text_series
    const float* Wq = (const float*)d_in[2];
    const float* Wk = (const float*)d_in[4];
    const float* Wv = (const float*)d_in[6];
    const float* bv = (const float*)d_in[7];
    // bq (d_in[3]) and bk (d_in[5]) provably do not affect the output.

    float* ws    = (float*)d_ws;
    float* maugv = ws + O_MAUGV;
    float* bvaug = ws + O_BVAUG;
    unsigned short* mhi = (unsigned short*)(ws + O_MHI);
    unsigned short* mlo = (unsigned short*)(ws + O_MLO);
    float* kp_t  = ws + O_KPT;
    float* st    = ws + O_ST;
    float* vsub  = ws + O_VSUB;
    float* mv    = ws + O_MV;
    float* stats = ws + O_STATS;
    int*   istats = (int*)stats;      // [0]=idx0, [1]=idx1
    float* w01    = stats + 8;        // w0[64], w1[64]

    build_maug<<<272, 256, 0, stream>>>(Wq, Wk, Wv, bv, mhi, mlo, maugv, bvaug);
    dim3 gT(LL / 32, EE / 32, BB);
    transpose_S<<<gT, 256, 0, stream>>>(S, st);
    gemm_mfma<<<(BB * LL) / 64, 256, 0, stream>>>(T, mhi, mlo, kp_t);
    vsub_kernel<<<(BB * LL) / 64, 256, 0, stream>>>(T, maugv, bvaug, vsub);
    xcorr_kernel<<<BB * CHUNKS, 256, 0, stream>>>(st, kp_t);
    ifft_kernel<<<BB, 256, 0, stream>>>(st, mv);
    argidx_kernel<<<1, 1024, 0, stream>>>(mv, istats);
    softmax_kernel<<<BB, 256, 0, stream>>>(mv, istats, w01);
    out_kernel<<<(2 * BB * LL * KK) / 256, 256, 0, stream>>>(vsub, istats, w01, (float*)d_out);
}